// Round 6
// baseline (5278.729 us; speedup 1.0000x reference)
//
#include <hip/hip_runtime.h>
#include <hip/hip_bf16.h>
#include <math.h>

#define B_    32
#define DIM_  384
#define HID_  1536
#define P_    196     // 14*14 tokens
#define T_    6272    // B_*P_
#define NC_   1000
#define KSTEM_ 768    // 3*16*16
#define DEPTH_ 18
#define SCALE_ 0.05103103630798288f  // 384^-0.5

typedef __attribute__((ext_vector_type(8))) short bf16x8;
typedef __attribute__((ext_vector_type(4))) float f32x4;

enum { GEPI_NONE = 0, GEPI_BIAS = 1, GEPI_GELU = 2, GEPI_RESID = 3 };

__device__ __forceinline__ float gelu_exact(float v) {
  return 0.5f * v * (1.0f + erff(v * 0.70710678118654752f));
}
__device__ __forceinline__ unsigned short f2bf(float x) {
  union { float f; unsigned u; } v; v.f = x;
  unsigned r = v.u + 0x7fffu + ((v.u >> 16) & 1u);
  return (unsigned short)(r >> 16);
}
__device__ __forceinline__ float bf2f(unsigned short h) {
  union { float f; unsigned u; } v; v.u = ((unsigned)h) << 16;
  return v.f;
}

// byte offset of bf16 element (row, k) in a [rows][32] bf16 LDS plane, XOR-swizzled
#define SWZB(row, k) ((((row) * 64) + ((k) * 2)) ^ ((((row) & 7)) << 4))

// ---------------------------------------------------------------------------
// bf16x3 MFMA GEMM, pipelined: C = A(MxK, f32) @ B^T(NxK, bf16 hi/lo planes).
// A split hi/lo on the fly during LDS staging. 256 threads = 4 waves (2x2),
// wave tile (BM/2)x(BN/2), K-step 32.
// Double-buffered LDS: ONE barrier per K-step; global loads for t+2 issued at
// end of iter t (issue-early), LDS writes for t+1 after MFMA (write-late) so
// HBM latency hides under the compute phase.  XCD-bijective block swizzle.
// ---------------------------------------------------------------------------
template <int BM, int BN, int EPI>
__global__ __launch_bounds__(256) void gemm2(
    const float* __restrict__ A,
    const unsigned short* __restrict__ Bh, const unsigned short* __restrict__ Bl,
    float* __restrict__ C, const float* __restrict__ bias,
    int M, int N, int K)
{
  constexpr int WM = BM / 2, WN = BN / 2, TMW = WM / 16, TNW = WN / 16;
  constexpr int TPRA = 256 / BM, EA = 32 / TPRA;   // f32 elems per thread (A)
  constexpr int TPRB = 256 / BN, EB = 32 / TPRB;   // bf16 elems per thread per plane (B)
  constexpr int STG = (BM + BN) * 128;             // bytes per stage

  __shared__ unsigned char smem[2 * STG];

  const int tid = threadIdx.x;
  const int lane = tid & 63;
  const int w = tid >> 6;
  const int wm = w >> 1, wn = w & 1;
  const int r16 = lane & 15, ksl = lane >> 4;

  // ---- XCD-bijective swizzle (m204): each XCD owns a contiguous id chunk;
  // consecutive ids share the same A row-panel (x-fastest flat order). ----
  const int nwg = gridDim.x * gridDim.y;
  const int hwid = blockIdx.y * gridDim.x + blockIdx.x;
  const int q8 = nwg >> 3, r8 = nwg & 7;
  const int xcd = hwid & 7, idx8 = hwid >> 3;
  const int newid = (xcd < r8 ? xcd * (q8 + 1) : r8 * (q8 + 1) + (xcd - r8) * q8) + idx8;
  const int m0 = (newid / gridDim.x) * BM;
  const int n0 = (newid % gridDim.x) * BN;

  const int arow = tid / TPRA, ak0 = (tid % TPRA) * EA;
  const int brow = tid / TPRB, bk0 = (tid % TPRB) * EB;

  const float* ag = A + (size_t)(m0 + arow) * K + ak0;
  const unsigned short* bgh = Bh + (size_t)(n0 + brow) * K + bk0;
  const unsigned short* bgl = Bl + (size_t)(n0 + brow) * K + bk0;

  float4 pa[EA / 4];
  uint4 pbh[EB / 8], pbl[EB / 8];

  auto loadA = [&](int kt) {
#pragma unroll
    for (int qq = 0; qq < EA / 4; ++qq) pa[qq] = *(const float4*)(ag + kt + 4 * qq);
  };
  auto loadB = [&](int kt) {
#pragma unroll
    for (int qq = 0; qq < EB / 8; ++qq) {
      pbh[qq] = *(const uint4*)(bgh + kt + 8 * qq);
      pbl[qq] = *(const uint4*)(bgl + kt + 8 * qq);
    }
  };
  auto storeAB = [&](int p) {
    unsigned char* sAh = smem + p * STG;
    unsigned char* sAl = sAh + BM * 64;
    unsigned char* sBh = sAh + BM * 128;
    unsigned char* sBl = sAh + BM * 128 + BN * 64;
#pragma unroll
    for (int qq = 0; qq < EA / 4; ++qq) {
      const float4 f = pa[qq];
      const unsigned short h0 = f2bf(f.x), h1 = f2bf(f.y), h2 = f2bf(f.z), h3 = f2bf(f.w);
      const unsigned short l0 = f2bf(f.x - bf2f(h0)), l1 = f2bf(f.y - bf2f(h1));
      const unsigned short l2 = f2bf(f.z - bf2f(h2)), l3 = f2bf(f.w - bf2f(h3));
      uint2 uh, ul;
      uh.x = (unsigned)h0 | ((unsigned)h1 << 16);
      uh.y = (unsigned)h2 | ((unsigned)h3 << 16);
      ul.x = (unsigned)l0 | ((unsigned)l1 << 16);
      ul.y = (unsigned)l2 | ((unsigned)l3 << 16);
      *(uint2*)(sAh + SWZB(arow, ak0 + 4 * qq)) = uh;
      *(uint2*)(sAl + SWZB(arow, ak0 + 4 * qq)) = ul;
    }
#pragma unroll
    for (int qq = 0; qq < EB / 8; ++qq) {
      *(uint4*)(sBh + SWZB(brow, bk0 + 8 * qq)) = pbh[qq];
      *(uint4*)(sBl + SWZB(brow, bk0 + 8 * qq)) = pbl[qq];
    }
  };

  f32x4 acc[TMW][TNW];
#pragma unroll
  for (int i = 0; i < TMW; ++i)
#pragma unroll
    for (int j = 0; j < TNW; ++j) {
      acc[i][j][0] = 0.f; acc[i][j][1] = 0.f; acc[i][j][2] = 0.f; acc[i][j][3] = 0.f;
    }

  // prologue: stage tile 0, issue loads for tile 1
  loadA(0); loadB(0);
  storeAB(0);
  __syncthreads();
  if (K > 32) { loadA(32); loadB(32); }

  for (int kt = 0; kt < K; kt += 32) {
    const int cur = (kt >> 5) & 1;
    const unsigned char* sAh = smem + cur * STG;
    const unsigned char* sAl = sAh + BM * 64;
    const unsigned char* sBh = sAh + BM * 128;
    const unsigned char* sBl = sAh + BM * 128 + BN * 64;

    bf16x8 a_h[TMW], a_l[TMW], b_h[TNW], b_l[TNW];
#pragma unroll
    for (int i = 0; i < TMW; ++i) {
      const int row = wm * WM + 16 * i + r16;
      a_h[i] = *(const bf16x8*)(sAh + SWZB(row, ksl * 8));
      a_l[i] = *(const bf16x8*)(sAl + SWZB(row, ksl * 8));
    }
#pragma unroll
    for (int j = 0; j < TNW; ++j) {
      const int row = wn * WN + 16 * j + r16;
      b_h[j] = *(const bf16x8*)(sBh + SWZB(row, ksl * 8));
      b_l[j] = *(const bf16x8*)(sBl + SWZB(row, ksl * 8));
    }
#pragma unroll
    for (int i = 0; i < TMW; ++i)
#pragma unroll
      for (int j = 0; j < TNW; ++j) {
        acc[i][j] = __builtin_amdgcn_mfma_f32_16x16x32_bf16(a_h[i], b_h[j], acc[i][j], 0, 0, 0);
        acc[i][j] = __builtin_amdgcn_mfma_f32_16x16x32_bf16(a_h[i], b_l[j], acc[i][j], 0, 0, 0);
        acc[i][j] = __builtin_amdgcn_mfma_f32_16x16x32_bf16(a_l[i], b_h[j], acc[i][j], 0, 0, 0);
      }

    if (kt + 32 < K) {
      storeAB(cur ^ 1);                 // write tile t+1 (regs, vmcnt waited here)
      if (kt + 64 < K) { loadA(kt + 64); loadB(kt + 64); }  // issue tile t+2
    }
    __syncthreads();
  }

  // epilogue: 16 consecutive cols per 16-lane group -> coalesced stores
#pragma unroll
  for (int i = 0; i < TMW; ++i) {
#pragma unroll
    for (int j = 0; j < TNW; ++j) {
      const int col = n0 + wn * WN + 16 * j + r16;
      float bv = 0.f;
      if constexpr (EPI == GEPI_BIAS || EPI == GEPI_GELU || EPI == GEPI_RESID)
        bv = bias[col];
#pragma unroll
      for (int r = 0; r < 4; ++r) {
        const int row = m0 + wm * WM + 16 * i + ksl * 4 + r;
        float v = acc[i][j][r];
        float* cp = &C[(size_t)row * N + col];
        if constexpr (EPI == GEPI_GELU) {
          *cp = gelu_exact(v + bv);
        } else if constexpr (EPI == GEPI_RESID) {
          *cp = *cp + v + bv;
        } else if constexpr (EPI == GEPI_BIAS) {
          *cp = v + bv;
        } else {
          *cp = v;
        }
      }
    }
  }
}

// ---------------------------------------------------------------------------
// prep kernels
// ---------------------------------------------------------------------------
// [L][R][C] f32 -> [L][C][R] bf16 hi/lo planes via 32x32 LDS tile.
__global__ __launch_bounds__(256) void tr_split_tiled(
    const float* __restrict__ src, unsigned short* __restrict__ dh,
    unsigned short* __restrict__ dl, int R, int C)
{
  __shared__ float tile[32][33];
  const int l  = blockIdx.z;
  const int c0 = blockIdx.x * 32, r0 = blockIdx.y * 32;
  const int tx = threadIdx.x & 31, ty = threadIdx.x >> 5;   // ty 0..7

#pragma unroll
  for (int i = 0; i < 4; ++i) {
    const int rl = ty + 8 * i;
    tile[rl][tx] = src[((size_t)l * R + r0 + rl) * C + c0 + tx];
  }
  __syncthreads();
#pragma unroll
  for (int i = 0; i < 4; ++i) {
    const int cl = ty + 8 * i;
    const float v = tile[tx][cl];          // (r0+tx, c0+cl)
    const unsigned short h = f2bf(v);
    const size_t oidx = ((size_t)l * C + c0 + cl) * R + r0 + tx;
    dh[oidx] = h;
    dl[oidx] = f2bf(v - bf2f(h));
  }
}

// split only (already [N][K])
__global__ void split_only(const float* __restrict__ src, unsigned short* __restrict__ dh,
                           unsigned short* __restrict__ dl, int n)
{
  const int i = blockIdx.x * 256 + threadIdx.x;
  if (i >= n) return;
  const float v = src[i];
  const unsigned short h = f2bf(v);
  dh[i] = h;
  dl[i] = f2bf(v - bf2f(h));
}

// dw_w [18][384][49] -> dwT [18][49][384] fp32
__global__ void tr_dw(const float* __restrict__ src, float* __restrict__ dst)
{
  const int idx = blockIdx.x * 256 + threadIdx.x;
  if (idx >= DEPTH_ * 49 * DIM_) return;
  const int l = idx / (49 * DIM_);
  const int rem = idx % (49 * DIM_);
  const int k = rem / DIM_, c = rem % DIM_;
  dst[idx] = src[((size_t)l * DIM_ + c) * 49 + k];
}

__global__ void im2col_stem(const float* __restrict__ x, float* __restrict__ patch)
{
  const int idx = blockIdx.x * 256 + threadIdx.x;
  if (idx >= T_ * KSTEM_) return;
  const int row = idx / KSTEM_;
  const int k   = idx % KSTEM_;
  const int b   = row / P_;
  const int pix = row % P_;
  const int py = pix / 14, px = pix % 14;
  const int c  = k >> 8;
  const int r  = k & 255;
  const int iy = r >> 4, ix = r & 15;
  patch[idx] = x[((size_t)b * 3 + c) * 50176 + (size_t)(py * 16 + iy) * 224 + (px * 16 + ix)];
}

__global__ void lat_init(const float* __restrict__ latent, float* __restrict__ lat)
{
  const int idx = blockIdx.x * 256 + threadIdx.x;
  if (idx < B_ * DIM_) lat[idx] = latent[idx % DIM_];
}

// ---------------------------------------------------------------------------
// Readout body (384 threads)
// ---------------------------------------------------------------------------
__device__ __forceinline__ void readout_body(
    int b, const float* __restrict__ kv, float* __restrict__ lat,
    const float* __restrict__ q_w, const float* __restrict__ out_w,
    const float* __restrict__ out_b, const float* __restrict__ lng,
    const float* __restrict__ lnb)
{
  const int tid = threadIdx.x;
  __shared__ float latS[DIM_], qS[DIM_], oS[DIM_], tS[DIM_];
  __shared__ float aS[P_];
  __shared__ float sS[256];
  __shared__ float redR[6], statR[2];

  latS[tid] = lat[b * DIM_ + tid];
  __syncthreads();

  {
    float acc = 0.f;
    for (int d = 0; d < DIM_; ++d) acc = fmaf(latS[d], q_w[d * DIM_ + tid], acc);
    qS[tid] = acc;
  }
  __syncthreads();

  float my_s = -3.4e38f;
  if (tid < P_) {
    const float* kr = kv + ((size_t)(b * P_ + tid)) * 768;
    float acc = 0.f;
    for (int d = 0; d < DIM_; ++d) acc = fmaf(qS[d], kr[d], acc);
    my_s = acc * SCALE_;
  }
  if (tid < 256) sS[tid] = my_s;
  __syncthreads();
  for (int off = 128; off > 0; off >>= 1) {
    if (tid < off) sS[tid] = fmaxf(sS[tid], sS[tid + off]);
    __syncthreads();
  }
  const float mx = sS[0];
  __syncthreads();
  const float ex = (tid < P_) ? expf(my_s - mx) : 0.f;
  if (tid < 256) sS[tid] = ex;
  __syncthreads();
  for (int off = 128; off > 0; off >>= 1) {
    if (tid < off) sS[tid] += sS[tid + off];
    __syncthreads();
  }
  const float den = sS[0];
  if (tid < P_) aS[tid] = ex / den;
  __syncthreads();

  {
    float acc = 0.f;
    for (int t = 0; t < P_; ++t)
      acc = fmaf(aS[t], kv[((size_t)(b * P_ + t)) * 768 + DIM_ + tid], acc);
    oS[tid] = acc;
  }
  __syncthreads();

  {
    float acc = out_b[tid] + latS[tid];
    for (int d = 0; d < DIM_; ++d) acc = fmaf(oS[d], out_w[d * DIM_ + tid], acc);
    tS[tid] = acc;
  }
  __syncthreads();

  const int lane = tid & 63, wv = tid >> 6;
  const float val = tS[tid];
  float s = val;
#pragma unroll
  for (int off = 32; off > 0; off >>= 1) s += __shfl_down(s, off);
  if (lane == 0) redR[wv] = s;
  __syncthreads();
  if (tid == 0) {
    float t = 0.f;
    for (int i = 0; i < 6; ++i) t += redR[i];
    statR[0] = t * (1.0f / DIM_);
  }
  __syncthreads();
  const float mu = statR[0];
  const float dv = val - mu;
  s = dv * dv;
#pragma unroll
  for (int off = 32; off > 0; off >>= 1) s += __shfl_down(s, off);
  if (lane == 0) redR[wv] = s;
  __syncthreads();
  if (tid == 0) {
    float t = 0.f;
    for (int i = 0; i < 6; ++i) t += redR[i];
    statR[1] = t * (1.0f / DIM_);
  }
  __syncthreads();
  const float inv = 1.0f / sqrtf(statR[1] + 1e-5f);
  lat[b * DIM_ + tid] = dv * inv * lng[tid] + lnb[tid];
}

// ---------------------------------------------------------------------------
// Fused: blocks [0,B_) readout (current kv); [B_, B_+T_) dwconv+LN -> f32 yb
// Branchless taps: clamp address, cndmask value -> all 49 loads in flight.
// ---------------------------------------------------------------------------
__global__ __launch_bounds__(384) void dwconv_readout(
    const float* __restrict__ h, const float* __restrict__ wT,
    const float* __restrict__ wb, const float* __restrict__ g,
    const float* __restrict__ beta, float* __restrict__ y,
    const float* __restrict__ kv, float* __restrict__ lat,
    const float* __restrict__ q_w, const float* __restrict__ out_w,
    const float* __restrict__ out_b, const float* __restrict__ lng,
    const float* __restrict__ lnb)
{
  if (blockIdx.x < B_) {
    readout_body(blockIdx.x, kv, lat, q_w, out_w, out_b, lng, lnb);
    return;
  }
  const int c = threadIdx.x;
  const int p = blockIdx.x - B_;
  const int b = p / P_, pix = p % P_;
  const int py = pix / 14, px = pix % 14;
  const float* hb = h + (size_t)b * P_ * DIM_;

  float acc = wb[c];
#pragma unroll
  for (int ky = 0; ky < 7; ++ky) {
    const int qy = py + ky - 3;
    const bool vy = (unsigned)qy < 14u;
    const int qyc = vy ? qy : 0;
#pragma unroll
    for (int kx = 0; kx < 7; ++kx) {
      const int qx = px + kx - 3;
      const bool v = vy && ((unsigned)qx < 14u);
      const int qxc = ((unsigned)qx < 14u) ? qx : 0;
      const float hv = hb[(size_t)(qyc * 14 + qxc) * DIM_ + c];
      acc = fmaf(v ? hv : 0.f, wT[(ky * 7 + kx) * DIM_ + c], acc);
    }
  }

  __shared__ float red[6];
  __shared__ float stat[2];
  const int lane = c & 63, wv = c >> 6;

  float s = acc;
#pragma unroll
  for (int off = 32; off > 0; off >>= 1) s += __shfl_down(s, off);
  if (lane == 0) red[wv] = s;
  __syncthreads();
  if (c == 0) {
    float t = 0.f;
    for (int i = 0; i < 6; ++i) t += red[i];
    stat[0] = t * (1.0f / DIM_);
  }
  __syncthreads();
  const float mu = stat[0];
  const float d = acc - mu;
  s = d * d;
#pragma unroll
  for (int off = 32; off > 0; off >>= 1) s += __shfl_down(s, off);
  if (lane == 0) red[wv] = s;
  __syncthreads();
  if (c == 0) {
    float t = 0.f;
    for (int i = 0; i < 6; ++i) t += red[i];
    stat[1] = t * (1.0f / DIM_);
  }
  __syncthreads();
  const float inv = 1.0f / sqrtf(stat[1] + 1e-6f);
  y[(size_t)p * DIM_ + c] = d * inv * g[c] + beta[c];
}

__global__ __launch_bounds__(384) void readout_attn(
    const float* __restrict__ kv, float* __restrict__ lat,
    const float* __restrict__ q_w, const float* __restrict__ out_w,
    const float* __restrict__ out_b, const float* __restrict__ lng,
    const float* __restrict__ lnb)
{
  readout_body(blockIdx.x, kv, lat, q_w, out_w, out_b, lng, lnb);
}

__global__ __launch_bounds__(256) void head_kernel(
    const float* __restrict__ lat, const float* __restrict__ hw,
    const float* __restrict__ hb, float* __restrict__ out)
{
  const int b = blockIdx.x;
  for (int n = threadIdx.x; n < NC_; n += 256) {
    float acc = hb[n];
    for (int d = 0; d < DIM_; ++d)
      acc = fmaf(lat[b * DIM_ + d], hw[(size_t)d * NC_ + n], acc);
    out[(size_t)b * NC_ + n] = acc;
  }
}

// ---------------------------------------------------------------------------
extern "C" void kernel_launch(void* const* d_in, const int* in_sizes, int n_in,
                              void* d_out, int out_size, void* d_ws, size_t ws_size,
                              hipStream_t stream)
{
  const float* x       = (const float*)d_in[0];
  const float* stem_w  = (const float*)d_in[1];
  const float* stem_b  = (const float*)d_in[2];
  const float* dw_w    = (const float*)d_in[3];
  const float* dw_b    = (const float*)d_in[4];
  const float* ln_g    = (const float*)d_in[5];
  const float* ln_b    = (const float*)d_in[6];
  const float* w1      = (const float*)d_in[7];
  const float* b1      = (const float*)d_in[8];
  const float* w2      = (const float*)d_in[9];
  const float* b2      = (const float*)d_in[10];
  const float* q_w     = (const float*)d_in[11];
  const float* kv_w    = (const float*)d_in[12];
  const float* out_w   = (const float*)d_in[13];
  const float* out_b   = (const float*)d_in[14];
  const float* latent  = (const float*)d_in[15];
  const float* lln_g   = (const float*)d_in[16];
  const float* lln_b   = (const float*)d_in[17];
  const float* head_w  = (const float*)d_in[18];
  const float* head_b  = (const float*)d_in[19];

  char* base = (char*)d_ws;
  size_t off = 0;
  auto alloc = [&](size_t bytes) {
    void* p = base + off;
    off += (bytes + 255) & ~(size_t)255;
    return p;
  };
  float* h     = (float*)alloc((size_t)T_ * DIM_ * 4);      // residual stream
  float* kvb   = (float*)alloc((size_t)T_ * 768 * 4);       // kv projections
  float* yb    = (float*)alloc((size_t)T_ * DIM_ * 4);      // dwconv+LN out
  float* hid   = (float*)alloc((size_t)T_ * HID_ * 4);      // MLP hidden (gelu'd)
  unsigned short* w1h = (unsigned short*)alloc((size_t)DEPTH_ * HID_ * DIM_ * 2);
  unsigned short* w1l = (unsigned short*)alloc((size_t)DEPTH_ * HID_ * DIM_ * 2);
  unsigned short* w2h = (unsigned short*)alloc((size_t)DEPTH_ * DIM_ * HID_ * 2);
  unsigned short* w2l = (unsigned short*)alloc((size_t)DEPTH_ * DIM_ * HID_ * 2);
  unsigned short* kvh = (unsigned short*)alloc((size_t)768 * DIM_ * 2);
  unsigned short* kvl = (unsigned short*)alloc((size_t)768 * DIM_ * 2);
  unsigned short* sth = (unsigned short*)alloc((size_t)DIM_ * KSTEM_ * 2);
  unsigned short* stl = (unsigned short*)alloc((size_t)DIM_ * KSTEM_ * 2);
  float* dwT   = (float*)alloc((size_t)DEPTH_ * 49 * DIM_ * 4);
  float* lat   = (float*)alloc((size_t)B_ * DIM_ * 4);
  float* patch = hid;   // T_*768*4 fits in T_*HID_*4; used only in prolog

  // ---- prep (all independent) ----
  im2col_stem<<<(T_ * KSTEM_ + 255) / 256, 256, 0, stream>>>(x, patch);
  split_only<<<(DIM_ * KSTEM_ + 255) / 256, 256, 0, stream>>>(stem_w, sth, stl, DIM_ * KSTEM_);
  tr_split_tiled<<<dim3(HID_ / 32, DIM_ / 32, DEPTH_), 256, 0, stream>>>(
      w1, w1h, w1l, DIM_, HID_);
  tr_split_tiled<<<dim3(DIM_ / 32, HID_ / 32, DEPTH_), 256, 0, stream>>>(
      w2, w2h, w2l, HID_, DIM_);
  tr_split_tiled<<<dim3(768 / 32, DIM_ / 32, 1), 256, 0, stream>>>(
      kv_w, kvh, kvl, DIM_, 768);
  tr_dw<<<(DEPTH_ * 49 * DIM_ + 255) / 256, 256, 0, stream>>>(dw_w, dwT);
  lat_init<<<(B_ * DIM_ + 255) / 256, 256, 0, stream>>>(latent, lat);

  // ---- stem: h = patch @ stemW^T + stem_b ----
  gemm2<128, 64, GEPI_BIAS><<<dim3(DIM_ / 64, T_ / 128), 256, 0, stream>>>(
      patch, sth, stl, h, stem_b, T_, DIM_, KSTEM_);

  // ---- kv for readout 0 ----
  gemm2<128, 128, GEPI_NONE><<<dim3(768 / 128, T_ / 128), 256, 0, stream>>>(
      h, kvh, kvl, kvb, nullptr, T_, 768, DIM_);

  // ---- blocks: [readout(l) || dwconv(l)] -> MLP1 -> MLP2(+resid) -> kv ----
  for (int l = 0; l < DEPTH_; ++l) {
    dwconv_readout<<<B_ + T_, 384, 0, stream>>>(
        h, dwT + (size_t)l * 49 * DIM_, dw_b + (size_t)l * DIM_,
        ln_g + (size_t)l * DIM_, ln_b + (size_t)l * DIM_, yb,
        kvb, lat, q_w, out_w, out_b, lln_g, lln_b);
    gemm2<128, 128, GEPI_GELU><<<dim3(HID_ / 128, T_ / 128), 256, 0, stream>>>(
        yb, w1h + (size_t)l * HID_ * DIM_, w1l + (size_t)l * HID_ * DIM_,
        hid, b1 + (size_t)l * HID_, T_, HID_, DIM_);
    gemm2<128, 64, GEPI_RESID><<<dim3(DIM_ / 64, T_ / 128), 256, 0, stream>>>(
        hid, w2h + (size_t)l * DIM_ * HID_, w2l + (size_t)l * DIM_ * HID_,
        h, b2 + (size_t)l * DIM_, T_, DIM_, HID_);
    gemm2<128, 128, GEPI_NONE><<<dim3(768 / 128, T_ / 128), 256, 0, stream>>>(
        h, kvh, kvl, kvb, nullptr, T_, 768, DIM_);
  }

  // final readout + head
  readout_attn<<<B_, 384, 0, stream>>>(kvb, lat, q_w, out_w, out_b, lln_g, lln_b);
  head_kernel<<<B_, 256, 0, stream>>>(lat, head_w, head_b, (float*)d_out);
}

// Round 8
// 3512.177 us; speedup vs baseline: 1.5030x; 1.5030x over previous
//
#include <hip/hip_runtime.h>
#include <hip/hip_bf16.h>
#include <math.h>

#define B_    32
#define DIM_  384
#define HID_  1536
#define P_    196     // 14*14 tokens
#define T_    6272    // B_*P_
#define NC_   1000
#define KSTEM_ 768    // 3*16*16
#define DEPTH_ 18
#define SCALE_ 0.05103103630798288f  // 384^-0.5

typedef __attribute__((ext_vector_type(8))) short bf16x8;
typedef __attribute__((ext_vector_type(4))) float f32x4;

enum { GEPI_NONE = 0, GEPI_BIAS = 1, GEPI_GELU = 2, GEPI_ATOMIC_BIAS = 3 };

__device__ __forceinline__ float gelu_exact(float v) {
  return 0.5f * v * (1.0f + erff(v * 0.70710678118654752f));
}
__device__ __forceinline__ unsigned short f2bf(float x) {
  union { float f; unsigned u; } v; v.f = x;
  unsigned r = v.u + 0x7fffu + ((v.u >> 16) & 1u);
  return (unsigned short)(r >> 16);
}
__device__ __forceinline__ float bf2f(unsigned short h) {
  union { float f; unsigned u; } v; v.u = ((unsigned)h) << 16;
  return v.f;
}

// byte offset of bf16 element (row, k) in a [rows][32] bf16 LDS plane, XOR-swizzled
#define SWZB(row, k) ((((row) * 64) + ((k) * 2)) ^ ((((row) & 7)) << 4))

// ---------------------------------------------------------------------------
// bf16x3 MFMA GEMM, 64x64 tile (latency-bound regime -> maximize TLP):
// C = A(MxK, f32) @ B^T(NxK, bf16 hi/lo planes). 256 threads = 4 waves (2x2),
// wave tile 32x32 (2x2 frags), K-step 32, double-buffered LDS (32KB -> 5
// blocks/CU), one barrier per K-step. Optional split-K via blockIdx.z with
// fp32 atomicAdd epilogue (used for MLP2: residual already in C).
// Three-pass MFMA order (hh,hl,lh) breaks acc dependency chains.
// ---------------------------------------------------------------------------
template <int EPI>
__global__ __launch_bounds__(256) void gemm3(
    const float* __restrict__ A,
    const unsigned short* __restrict__ Bh, const unsigned short* __restrict__ Bl,
    float* __restrict__ C, const float* __restrict__ bias,
    int M, int N, int K, int KS)
{
  constexpr int BM = 64, BN = 64;
  constexpr int TMW = 2, TNW = 2;                 // 32x32 wave tile
  constexpr int STG = (BM + BN) * 128;            // 16KB per stage

  __shared__ unsigned char smem[2 * STG];

  const int tid = threadIdx.x;
  const int lane = tid & 63;
  const int w = tid >> 6;
  const int wm = w >> 1, wn = w & 1;
  const int r16 = lane & 15, ksl = lane >> 4;

  // XCD-bijective swizzle within each z-slice (m204)
  const int nwg = gridDim.x * gridDim.y;
  const int hwid = blockIdx.y * gridDim.x + blockIdx.x;
  const int q8 = nwg >> 3, r8 = nwg & 7;
  const int xcd = hwid & 7, idx8 = hwid >> 3;
  const int newid = (xcd < r8 ? xcd * (q8 + 1) : r8 * (q8 + 1) + (xcd - r8) * q8) + idx8;
  const int m0 = (newid / gridDim.x) * BM;
  const int n0 = (newid % gridDim.x) * BN;

  const int kbeg = blockIdx.z * KS;
  const int kend = kbeg + KS;

  // staging: 4 threads per row, 8 contiguous elems each
  const int arow = tid >> 2, ak0 = (tid & 3) * 8;
  const int brow = tid >> 2, bk0 = (tid & 3) * 8;

  const float* ag = A + (size_t)(m0 + arow) * K + ak0;
  const unsigned short* bgh = Bh + (size_t)(n0 + brow) * K + bk0;
  const unsigned short* bgl = Bl + (size_t)(n0 + brow) * K + bk0;

  float4 pa[2];
  uint4 pbh, pbl;

  auto loadAB = [&](int kt) {
    pa[0] = *(const float4*)(ag + kt);
    pa[1] = *(const float4*)(ag + kt + 4);
    pbh = *(const uint4*)(bgh + kt);
    pbl = *(const uint4*)(bgl + kt);
  };
  auto storeAB = [&](int p) {
    unsigned char* sAh = smem + p * STG;
    unsigned char* sAl = sAh + BM * 64;
    unsigned char* sBh = sAh + BM * 128;
    unsigned char* sBl = sAh + BM * 128 + BN * 64;
#pragma unroll
    for (int qq = 0; qq < 2; ++qq) {
      const float4 f = pa[qq];
      const unsigned short h0 = f2bf(f.x), h1 = f2bf(f.y), h2 = f2bf(f.z), h3 = f2bf(f.w);
      const unsigned short l0 = f2bf(f.x - bf2f(h0)), l1 = f2bf(f.y - bf2f(h1));
      const unsigned short l2 = f2bf(f.z - bf2f(h2)), l3 = f2bf(f.w - bf2f(h3));
      uint2 uh, ul;
      uh.x = (unsigned)h0 | ((unsigned)h1 << 16);
      uh.y = (unsigned)h2 | ((unsigned)h3 << 16);
      ul.x = (unsigned)l0 | ((unsigned)l1 << 16);
      ul.y = (unsigned)l2 | ((unsigned)l3 << 16);
      *(uint2*)(sAh + SWZB(arow, ak0 + 4 * qq)) = uh;
      *(uint2*)(sAl + SWZB(arow, ak0 + 4 * qq)) = ul;
    }
    *(uint4*)(sBh + SWZB(brow, bk0)) = pbh;
    *(uint4*)(sBl + SWZB(brow, bk0)) = pbl;
  };

  f32x4 acc[TMW][TNW];
#pragma unroll
  for (int i = 0; i < TMW; ++i)
#pragma unroll
    for (int j = 0; j < TNW; ++j) {
      acc[i][j][0] = 0.f; acc[i][j][1] = 0.f; acc[i][j][2] = 0.f; acc[i][j][3] = 0.f;
    }

  loadAB(kbeg);
  storeAB(0);
  __syncthreads();
  if (kbeg + 32 < kend) loadAB(kbeg + 32);

  for (int kt = kbeg; kt < kend; kt += 32) {
    const int cur = ((kt - kbeg) >> 5) & 1;
    const unsigned char* sAh = smem + cur * STG;
    const unsigned char* sAl = sAh + BM * 64;
    const unsigned char* sBh = sAh + BM * 128;
    const unsigned char* sBl = sAh + BM * 128 + BN * 64;

    bf16x8 a_h[TMW], a_l[TMW], b_h[TNW], b_l[TNW];
#pragma unroll
    for (int i = 0; i < TMW; ++i) {
      const int row = wm * 32 + 16 * i + r16;
      a_h[i] = *(const bf16x8*)(sAh + SWZB(row, ksl * 8));
      a_l[i] = *(const bf16x8*)(sAl + SWZB(row, ksl * 8));
    }
#pragma unroll
    for (int j = 0; j < TNW; ++j) {
      const int row = wn * 32 + 16 * j + r16;
      b_h[j] = *(const bf16x8*)(sBh + SWZB(row, ksl * 8));
      b_l[j] = *(const bf16x8*)(sBl + SWZB(row, ksl * 8));
    }
    // three passes: consecutive MFMAs independent (no acc chain back-to-back)
#pragma unroll
    for (int i = 0; i < TMW; ++i)
#pragma unroll
      for (int j = 0; j < TNW; ++j)
        acc[i][j] = __builtin_amdgcn_mfma_f32_16x16x32_bf16(a_h[i], b_h[j], acc[i][j], 0, 0, 0);
#pragma unroll
    for (int i = 0; i < TMW; ++i)
#pragma unroll
      for (int j = 0; j < TNW; ++j)
        acc[i][j] = __builtin_amdgcn_mfma_f32_16x16x32_bf16(a_h[i], b_l[j], acc[i][j], 0, 0, 0);
#pragma unroll
    for (int i = 0; i < TMW; ++i)
#pragma unroll
      for (int j = 0; j < TNW; ++j)
        acc[i][j] = __builtin_amdgcn_mfma_f32_16x16x32_bf16(a_l[i], b_h[j], acc[i][j], 0, 0, 0);

    if (kt + 32 < kend) {
      storeAB(cur ^ 1);                          // write t+1 (waits its loads)
      if (kt + 64 < kend) loadAB(kt + 64);       // issue t+2
    }
    __syncthreads();
  }

#pragma unroll
  for (int i = 0; i < TMW; ++i) {
#pragma unroll
    for (int j = 0; j < TNW; ++j) {
      const int col = n0 + wn * 32 + 16 * j + r16;
      float bv = 0.f;
      if constexpr (EPI == GEPI_BIAS || EPI == GEPI_GELU) bv = bias[col];
      else if constexpr (EPI == GEPI_ATOMIC_BIAS) bv = (blockIdx.z == 0) ? bias[col] : 0.f;
#pragma unroll
      for (int r = 0; r < 4; ++r) {
        const int row = m0 + wm * 32 + 16 * i + ksl * 4 + r;
        float v = acc[i][j][r];
        float* cp = &C[(size_t)row * N + col];
        if constexpr (EPI == GEPI_GELU) {
          *cp = gelu_exact(v + bv);
        } else if constexpr (EPI == GEPI_ATOMIC_BIAS) {
          atomicAdd(cp, v + bv);
        } else if constexpr (EPI == GEPI_BIAS) {
          *cp = v + bv;
        } else {
          *cp = v;
        }
      }
    }
  }
}

// ---------------------------------------------------------------------------
// prep kernels
// ---------------------------------------------------------------------------
// [L][R][C] f32 -> [L][C][R] bf16 hi/lo planes via 32x32 LDS tile.
__global__ __launch_bounds__(256) void tr_split_tiled(
    const float* __restrict__ src, unsigned short* __restrict__ dh,
    unsigned short* __restrict__ dl, int R, int C)
{
  __shared__ float tile[32][33];
  const int l  = blockIdx.z;
  const int c0 = blockIdx.x * 32, r0 = blockIdx.y * 32;
  const int tx = threadIdx.x & 31, ty = threadIdx.x >> 5;   // ty 0..7

#pragma unroll
  for (int i = 0; i < 4; ++i) {
    const int rl = ty + 8 * i;
    tile[rl][tx] = src[((size_t)l * R + r0 + rl) * C + c0 + tx];
  }
  __syncthreads();
#pragma unroll
  for (int i = 0; i < 4; ++i) {
    const int cl = ty + 8 * i;
    const float v = tile[tx][cl];          // (r0+tx, c0+cl)
    const unsigned short h = f2bf(v);
    const size_t oidx = ((size_t)l * C + c0 + cl) * R + r0 + tx;
    dh[oidx] = h;
    dl[oidx] = f2bf(v - bf2f(h));
  }
}

// split only (already [N][K])
__global__ void split_only(const float* __restrict__ src, unsigned short* __restrict__ dh,
                           unsigned short* __restrict__ dl, int n)
{
  const int i = blockIdx.x * 256 + threadIdx.x;
  if (i >= n) return;
  const float v = src[i];
  const unsigned short h = f2bf(v);
  dh[i] = h;
  dl[i] = f2bf(v - bf2f(h));
}

// dw_w [18][384][49] -> dwT [18][49][384] fp32
__global__ void tr_dw(const float* __restrict__ src, float* __restrict__ dst)
{
  const int idx = blockIdx.x * 256 + threadIdx.x;
  if (idx >= DEPTH_ * 49 * DIM_) return;
  const int l = idx / (49 * DIM_);
  const int rem = idx % (49 * DIM_);
  const int k = rem / DIM_, c = rem % DIM_;
  dst[idx] = src[((size_t)l * DIM_ + c) * 49 + k];
}

__global__ void im2col_stem(const float* __restrict__ x, float* __restrict__ patch)
{
  const int idx = blockIdx.x * 256 + threadIdx.x;
  if (idx >= T_ * KSTEM_) return;
  const int row = idx / KSTEM_;
  const int k   = idx % KSTEM_;
  const int b   = row / P_;
  const int pix = row % P_;
  const int py = pix / 14, px = pix % 14;
  const int c  = k >> 8;
  const int r  = k & 255;
  const int iy = r >> 4, ix = r & 15;
  patch[idx] = x[((size_t)b * 3 + c) * 50176 + (size_t)(py * 16 + iy) * 224 + (px * 16 + ix)];
}

__global__ void lat_init(const float* __restrict__ latent, float* __restrict__ lat)
{
  const int idx = blockIdx.x * 256 + threadIdx.x;
  if (idx < B_ * DIM_) lat[idx] = latent[idx % DIM_];
}

// ---------------------------------------------------------------------------
// Readout body (384 threads)
// ---------------------------------------------------------------------------
__device__ __forceinline__ void readout_body(
    int b, const float* __restrict__ kv, float* __restrict__ lat,
    const float* __restrict__ q_w, const float* __restrict__ out_w,
    const float* __restrict__ out_b, const float* __restrict__ lng,
    const float* __restrict__ lnb)
{
  const int tid = threadIdx.x;
  __shared__ float latS[DIM_], qS[DIM_], oS[DIM_], tS[DIM_];
  __shared__ float aS[P_];
  __shared__ float sS[256];
  __shared__ float redR[6], statR[2];

  latS[tid] = lat[b * DIM_ + tid];
  __syncthreads();

  {
    float acc = 0.f;
    for (int d = 0; d < DIM_; ++d) acc = fmaf(latS[d], q_w[d * DIM_ + tid], acc);
    qS[tid] = acc;
  }
  __syncthreads();

  float my_s = -3.4e38f;
  if (tid < P_) {
    const float* kr = kv + ((size_t)(b * P_ + tid)) * 768;
    float acc = 0.f;
    for (int d = 0; d < DIM_; ++d) acc = fmaf(qS[d], kr[d], acc);
    my_s = acc * SCALE_;
  }
  if (tid < 256) sS[tid] = my_s;
  __syncthreads();
  for (int off = 128; off > 0; off >>= 1) {
    if (tid < off) sS[tid] = fmaxf(sS[tid], sS[tid + off]);
    __syncthreads();
  }
  const float mx = sS[0];
  __syncthreads();
  const float ex = (tid < P_) ? expf(my_s - mx) : 0.f;
  if (tid < 256) sS[tid] = ex;
  __syncthreads();
  for (int off = 128; off > 0; off >>= 1) {
    if (tid < off) sS[tid] += sS[tid + off];
    __syncthreads();
  }
  const float den = sS[0];
  if (tid < P_) aS[tid] = ex / den;
  __syncthreads();

  {
    float acc = 0.f;
    for (int t = 0; t < P_; ++t)
      acc = fmaf(aS[t], kv[((size_t)(b * P_ + t)) * 768 + DIM_ + tid], acc);
    oS[tid] = acc;
  }
  __syncthreads();

  {
    float acc = out_b[tid] + latS[tid];
    for (int d = 0; d < DIM_; ++d) acc = fmaf(oS[d], out_w[d * DIM_ + tid], acc);
    tS[tid] = acc;
  }
  __syncthreads();

  const int lane = tid & 63, wv = tid >> 6;
  const float val = tS[tid];
  float s = val;
#pragma unroll
  for (int off = 32; off > 0; off >>= 1) s += __shfl_down(s, off);
  if (lane == 0) redR[wv] = s;
  __syncthreads();
  if (tid == 0) {
    float t = 0.f;
    for (int i = 0; i < 6; ++i) t += redR[i];
    statR[0] = t * (1.0f / DIM_);
  }
  __syncthreads();
  const float mu = statR[0];
  const float dv = val - mu;
  s = dv * dv;
#pragma unroll
  for (int off = 32; off > 0; off >>= 1) s += __shfl_down(s, off);
  if (lane == 0) redR[wv] = s;
  __syncthreads();
  if (tid == 0) {
    float t = 0.f;
    for (int i = 0; i < 6; ++i) t += redR[i];
    statR[1] = t * (1.0f / DIM_);
  }
  __syncthreads();
  const float inv = 1.0f / sqrtf(statR[1] + 1e-5f);
  lat[b * DIM_ + tid] = dv * inv * lng[tid] + lnb[tid];
}

// ---------------------------------------------------------------------------
// Fused: blocks [0,B_) readout (current kv); [B_, B_+T_) dwconv+LN -> f32 yb
// ---------------------------------------------------------------------------
__global__ __launch_bounds__(384) void dwconv_readout(
    const float* __restrict__ h, const float* __restrict__ wT,
    const float* __restrict__ wb, const float* __restrict__ g,
    const float* __restrict__ beta, float* __restrict__ y,
    const float* __restrict__ kv, float* __restrict__ lat,
    const float* __restrict__ q_w, const float* __restrict__ out_w,
    const float* __restrict__ out_b, const float* __restrict__ lng,
    const float* __restrict__ lnb)
{
  if (blockIdx.x < B_) {
    readout_body(blockIdx.x, kv, lat, q_w, out_w, out_b, lng, lnb);
    return;
  }
  const int c = threadIdx.x;
  const int p = blockIdx.x - B_;
  const int b = p / P_, pix = p % P_;
  const int py = pix / 14, px = pix % 14;
  const float* hb = h + (size_t)b * P_ * DIM_;

  float acc = wb[c];
#pragma unroll
  for (int ky = 0; ky < 7; ++ky) {
    const int qy = py + ky - 3;
    const bool vy = (unsigned)qy < 14u;
    const int qyc = vy ? qy : 0;
#pragma unroll
    for (int kx = 0; kx < 7; ++kx) {
      const int qx = px + kx - 3;
      const bool v = vy && ((unsigned)qx < 14u);
      const int qxc = ((unsigned)qx < 14u) ? qx : 0;
      const float hv = hb[(size_t)(qyc * 14 + qxc) * DIM_ + c];
      acc = fmaf(v ? hv : 0.f, wT[(ky * 7 + kx) * DIM_ + c], acc);
    }
  }

  __shared__ float red[6];
  __shared__ float stat[2];
  const int lane = c & 63, wv = c >> 6;

  float s = acc;
#pragma unroll
  for (int off = 32; off > 0; off >>= 1) s += __shfl_down(s, off);
  if (lane == 0) red[wv] = s;
  __syncthreads();
  if (c == 0) {
    float t = 0.f;
    for (int i = 0; i < 6; ++i) t += red[i];
    stat[0] = t * (1.0f / DIM_);
  }
  __syncthreads();
  const float mu = stat[0];
  const float d = acc - mu;
  s = d * d;
#pragma unroll
  for (int off = 32; off > 0; off >>= 1) s += __shfl_down(s, off);
  if (lane == 0) red[wv] = s;
  __syncthreads();
  if (c == 0) {
    float t = 0.f;
    for (int i = 0; i < 6; ++i) t += red[i];
    stat[1] = t * (1.0f / DIM_);
  }
  __syncthreads();
  const float inv = 1.0f / sqrtf(stat[1] + 1e-6f);
  y[(size_t)p * DIM_ + c] = d * inv * g[c] + beta[c];
}

__global__ __launch_bounds__(384) void readout_attn(
    const float* __restrict__ kv, float* __restrict__ lat,
    const float* __restrict__ q_w, const float* __restrict__ out_w,
    const float* __restrict__ out_b, const float* __restrict__ lng,
    const float* __restrict__ lnb)
{
  readout_body(blockIdx.x, kv, lat, q_w, out_w, out_b, lng, lnb);
}

__global__ __launch_bounds__(256) void head_kernel(
    const float* __restrict__ lat, const float* __restrict__ hw,
    const float* __restrict__ hb, float* __restrict__ out)
{
  const int b = blockIdx.x;
  for (int n = threadIdx.x; n < NC_; n += 256) {
    float acc = hb[n];
    for (int d = 0; d < DIM_; ++d)
      acc = fmaf(lat[b * DIM_ + d], hw[(size_t)d * NC_ + n], acc);
    out[(size_t)b * NC_ + n] = acc;
  }
}

// ---------------------------------------------------------------------------
extern "C" void kernel_launch(void* const* d_in, const int* in_sizes, int n_in,
                              void* d_out, int out_size, void* d_ws, size_t ws_size,
                              hipStream_t stream)
{
  const float* x       = (const float*)d_in[0];
  const float* stem_w  = (const float*)d_in[1];
  const float* stem_b  = (const float*)d_in[2];
  const float* dw_w    = (const float*)d_in[3];
  const float* dw_b    = (const float*)d_in[4];
  const float* ln_g    = (const float*)d_in[5];
  const float* ln_b    = (const float*)d_in[6];
  const float* w1      = (const float*)d_in[7];
  const float* b1      = (const float*)d_in[8];
  const float* w2      = (const float*)d_in[9];
  const float* b2      = (const float*)d_in[10];
  const float* q_w     = (const float*)d_in[11];
  const float* kv_w    = (const float*)d_in[12];
  const float* out_w   = (const float*)d_in[13];
  const float* out_b   = (const float*)d_in[14];
  const float* latent  = (const float*)d_in[15];
  const float* lln_g   = (const float*)d_in[16];
  const float* lln_b   = (const float*)d_in[17];
  const float* head_w  = (const float*)d_in[18];
  const float* head_b  = (const float*)d_in[19];

  char* base = (char*)d_ws;
  size_t off = 0;
  auto alloc = [&](size_t bytes) {
    void* p = base + off;
    off += (bytes + 255) & ~(size_t)255;
    return p;
  };
  float* h     = (float*)alloc((size_t)T_ * DIM_ * 4);      // residual stream
  float* kvb   = (float*)alloc((size_t)T_ * 768 * 4);       // kv projections
  float* yb    = (float*)alloc((size_t)T_ * DIM_ * 4);      // dwconv+LN out
  float* hid   = (float*)alloc((size_t)T_ * HID_ * 4);      // MLP hidden (gelu'd)
  unsigned short* w1h = (unsigned short*)alloc((size_t)DEPTH_ * HID_ * DIM_ * 2);
  unsigned short* w1l = (unsigned short*)alloc((size_t)DEPTH_ * HID_ * DIM_ * 2);
  unsigned short* w2h = (unsigned short*)alloc((size_t)DEPTH_ * DIM_ * HID_ * 2);
  unsigned short* w2l = (unsigned short*)alloc((size_t)DEPTH_ * DIM_ * HID_ * 2);
  unsigned short* kvh = (unsigned short*)alloc((size_t)768 * DIM_ * 2);
  unsigned short* kvl = (unsigned short*)alloc((size_t)768 * DIM_ * 2);
  unsigned short* sth = (unsigned short*)alloc((size_t)DIM_ * KSTEM_ * 2);
  unsigned short* stl = (unsigned short*)alloc((size_t)DIM_ * KSTEM_ * 2);
  float* dwT   = (float*)alloc((size_t)DEPTH_ * 49 * DIM_ * 4);
  float* lat   = (float*)alloc((size_t)B_ * DIM_ * 4);
  float* patch = hid;   // T_*768*4 fits in T_*HID_*4; used only in prolog

  // ---- prep (all independent) ----
  im2col_stem<<<(T_ * KSTEM_ + 255) / 256, 256, 0, stream>>>(x, patch);
  split_only<<<(DIM_ * KSTEM_ + 255) / 256, 256, 0, stream>>>(stem_w, sth, stl, DIM_ * KSTEM_);
  tr_split_tiled<<<dim3(HID_ / 32, DIM_ / 32, DEPTH_), 256, 0, stream>>>(
      w1, w1h, w1l, DIM_, HID_);
  tr_split_tiled<<<dim3(DIM_ / 32, HID_ / 32, DEPTH_), 256, 0, stream>>>(
      w2, w2h, w2l, HID_, DIM_);
  tr_split_tiled<<<dim3(768 / 32, DIM_ / 32, 1), 256, 0, stream>>>(
      kv_w, kvh, kvl, DIM_, 768);
  tr_dw<<<(DEPTH_ * 49 * DIM_ + 255) / 256, 256, 0, stream>>>(dw_w, dwT);
  lat_init<<<(B_ * DIM_ + 255) / 256, 256, 0, stream>>>(latent, lat);

  // ---- stem: h = patch @ stemW^T + stem_b ----
  gemm3<GEPI_BIAS><<<dim3(DIM_ / 64, T_ / 64), 256, 0, stream>>>(
      patch, sth, stl, h, stem_b, T_, DIM_, KSTEM_, KSTEM_);

  // ---- kv for readout 0 ----
  gemm3<GEPI_NONE><<<dim3(768 / 64, T_ / 64), 256, 0, stream>>>(
      h, kvh, kvl, kvb, nullptr, T_, 768, DIM_, DIM_);

  // ---- blocks: [readout(l) || dwconv(l)] -> MLP1 -> MLP2(splitK atomics) -> kv
  for (int l = 0; l < DEPTH_; ++l) {
    dwconv_readout<<<B_ + T_, 384, 0, stream>>>(
        h, dwT + (size_t)l * 49 * DIM_, dw_b + (size_t)l * DIM_,
        ln_g + (size_t)l * DIM_, ln_b + (size_t)l * DIM_, yb,
        kvb, lat, q_w, out_w, out_b, lln_g, lln_b);
    gemm3<GEPI_GELU><<<dim3(HID_ / 64, T_ / 64), 256, 0, stream>>>(
        yb, w1h + (size_t)l * HID_ * DIM_, w1l + (size_t)l * HID_ * DIM_,
        hid, b1 + (size_t)l * HID_, T_, HID_, DIM_, DIM_);
    // MLP2: split-K=4, atomicAdd into h (residual already present)
    gemm3<GEPI_ATOMIC_BIAS><<<dim3(DIM_ / 64, T_ / 64, 4), 256, 0, stream>>>(
        hid, w2h + (size_t)l * DIM_ * HID_, w2l + (size_t)l * DIM_ * HID_,
        h, b2 + (size_t)l * DIM_, T_, DIM_, HID_, HID_ / 4);
    gemm3<GEPI_NONE><<<dim3(768 / 64, T_ / 64), 256, 0, stream>>>(
        h, kvh, kvl, kvb, nullptr, T_, 768, DIM_, DIM_);
  }

  // final readout + head
  readout_attn<<<B_, 384, 0, stream>>>(kvb, lat, q_w, out_w, out_b, lln_g, lln_b);
  head_kernel<<<B_, 256, 0, stream>>>(lat, head_w, head_b, (float*)d_out);
}